// Round 5
// baseline (624.187 us; speedup 1.0000x reference)
//
#include <hip/hip_runtime.h>
#include <cstdint>

#define S_LEN 2048
#define EMB   2048
#define NHEAD 16
#define HDIM  128
#define NFUSE 2304   // fused proj width: 2048 q | 128 k | 128 v
#define LOG2E 1.4426950408889634f

typedef __attribute__((ext_vector_type(8))) short short8;
typedef __attribute__((ext_vector_type(4))) short short4v;
typedef __attribute__((ext_vector_type(8))) _Float16 half8;
typedef __attribute__((ext_vector_type(4))) float f32x4;
typedef unsigned int u32;

// round-to-nearest-even float -> bf16 (finite inputs)
__device__ inline short f2bf(float x) {
  union { float f; uint32_t u; } v; v.f = x;
  uint32_t r = v.u + 0x7fffu + ((v.u >> 16) & 1u);
  return (short)(r >> 16);
}
__device__ inline float bf2f(short b) {
  union { uint32_t u; float f; } v; v.u = ((uint32_t)(uint16_t)b) << 16;
  return v.f;
}
// raw v_exp_f32 (2^x); inputs pre-scaled to log2 domain
__device__ inline float fexp2(float x) {
  float r;
  __asm__ volatile("v_exp_f32 %0, %1" : "=v"(r) : "v"(x));
  return r;
}
// async global->LDS, 16B per lane; lds base must be wave-uniform
__device__ inline void glds16(const void* g, const short* l) {
  __builtin_amdgcn_global_load_lds(
      (const __attribute__((address_space(1))) u32*)g,
      (__attribute__((address_space(3))) u32*)l, 16, 0, 0);
}

// ---------------------------------------------------------------------------
// W1 group-reduce -> Wkv f32 [2048][256] (k cols 0..127, v cols 128..255)
// ---------------------------------------------------------------------------
__global__ __launch_bounds__(256) void reduce_w1_kernel(
    const float* __restrict__ W1, float* __restrict__ Wkv) {
  int idx = blockIdx.x * 256 + threadIdx.x;
  int i = idx >> 8;
  int c = idx & 255;
  int base = (c < 128) ? c : (c + 384);
  const float* r = W1 + (size_t)i * 1024 + base;
  Wkv[idx] = (r[0] + r[128]) + (r[256] + r[384]);
}

// ---------------------------------------------------------------------------
// elementwise split f32 -> (hi, lo) bf16; 4 elements/thread
// ---------------------------------------------------------------------------
__global__ __launch_bounds__(256) void split_f32_kernel(
    const float* __restrict__ src, short* __restrict__ hi,
    short* __restrict__ lo) {
  size_t idx = (size_t)blockIdx.x * 256 + threadIdx.x;
  float4 v = *(const float4*)(src + idx * 4);
  float vv[4] = {v.x, v.y, v.z, v.w};
  short4v h4, l4;
#pragma unroll
  for (int j = 0; j < 4; ++j) {
    short h = f2bf(vv[j]);
    h4[j] = h;
    l4[j] = f2bf(vv[j] - bf2f(h));
  }
  *(short4v*)(hi + idx * 4) = h4;
  *(short4v*)(lo + idx * 4) = l4;
}

// ---------------------------------------------------------------------------
// tiled transpose f32 W[K][N] -> T[N][K]; MODE 0: split bf16 (Th,Tl),
// MODE 1: fp16 bits into Th. grid (N/64, K/64), 256 threads
// ---------------------------------------------------------------------------
template <int MODE>
__global__ __launch_bounds__(256) void transpose_split_kernel(
    const float* __restrict__ W, short* __restrict__ Th,
    short* __restrict__ Tl, int K, int N) {
  __shared__ float T[64][65];
  const int tid = threadIdx.x;
  const int k0 = blockIdx.y * 64, n0 = blockIdx.x * 64;
  {
    int r = tid >> 2, c0 = (tid & 3) * 16;
    const float* src = W + (size_t)(k0 + r) * N + n0 + c0;
#pragma unroll
    for (int j = 0; j < 4; ++j) {
      float4 v = *(const float4*)(src + 4 * j);
      T[r][c0 + 4 * j + 0] = v.x; T[r][c0 + 4 * j + 1] = v.y;
      T[r][c0 + 4 * j + 2] = v.z; T[r][c0 + 4 * j + 3] = v.w;
    }
  }
  __syncthreads();
  {
    int n = tid >> 2, kc = (tid & 3) * 16;
    short8 h0, h1, l0, l1;
#pragma unroll
    for (int i = 0; i < 8; ++i) {
      float a = T[kc + i][n];
      float b = T[kc + 8 + i][n];
      if (MODE == 0) {
        short ha = f2bf(a), hb = f2bf(b);
        h0[i] = ha; h1[i] = hb;
        l0[i] = f2bf(a - bf2f(ha)); l1[i] = f2bf(b - bf2f(hb));
      } else {
        union { _Float16 h; short s; } ca, cb;
        ca.h = (_Float16)a; cb.h = (_Float16)b;
        h0[i] = ca.s; h1[i] = cb.s;
      }
    }
    size_t off = (size_t)(n0 + n) * K + k0 + kc;
    *(short8*)(Th + off) = h0;
    *(short8*)(Th + off + 8) = h1;
    if (MODE == 0) {
      *(short8*)(Tl + off) = l0;
      *(short8*)(Tl + off + 8) = l1;
    }
  }
}

// ---------------------------------------------------------------------------
// MFMA GEMM. SPLIT=true: A/Bt are bf16 (hi,lo), 3-term product (fp32-accurate),
// epilogue writes fp16 Cf (cols < qlim pre-scaled by log2e).
// SPLIT=false: A/Bt hold fp16 bits, single f16 MFMA, f32 C out.
// 128x128 tile, BK=32, 4 waves; global_load_lds width-16 staging.
// ---------------------------------------------------------------------------
template <bool SPLIT>
__global__ __launch_bounds__(256, 2) void gemm_mfma(
    const short* __restrict__ Ah, const short* __restrict__ Al,
    const short* __restrict__ Bth, const short* __restrict__ Btl,
    float* __restrict__ C, _Float16* __restrict__ Cf,
    int M, int N, int K, int qlim) {
  extern __shared__ short sm[];
  short* AhS = sm;            // [128][32]
  short* BhS = sm + 4096;
  short* AlS = sm + 8192;     // (SPLIT only)
  short* BlS = sm + 12288;

  const int tid  = threadIdx.x;
  const int w    = tid >> 6;
  const int lane = tid & 63;
  const int quad = lane >> 4, col16 = lane & 15;
  const int row0 = blockIdx.y * 128, col0 = blockIdx.x * 128;
  const float esc = (col0 < qlim) ? LOG2E : 1.0f;

  const int srow  = w * 32 + (lane >> 2);
  const int kpart = (lane & 3) * 8;
  const short* pAh0 = Ah + (size_t)(row0 + srow) * K + kpart;
  const short* pAh1 = pAh0 + (size_t)16 * K;
  const short* pBh0 = Bth + (size_t)(col0 + srow) * K + kpart;
  const short* pBh1 = pBh0 + (size_t)16 * K;
  const short* pAl0 = SPLIT ? Al + (size_t)(row0 + srow) * K + kpart : nullptr;
  const short* pAl1 = SPLIT ? pAl0 + (size_t)16 * K : nullptr;
  const short* pBl0 = SPLIT ? Btl + (size_t)(col0 + srow) * K + kpart : nullptr;
  const short* pBl1 = SPLIT ? pBl0 + (size_t)16 * K : nullptr;
  short* lA0 = AhS + (w * 32) * 32;
  short* lA1 = AhS + (w * 32 + 16) * 32;
  short* lB0 = BhS + (w * 32) * 32;
  short* lB1 = BhS + (w * 32 + 16) * 32;

  f32x4 acc[2][8];
#pragma unroll
  for (int mt = 0; mt < 2; ++mt)
#pragma unroll
    for (int nt = 0; nt < 8; ++nt) {
      acc[mt][nt][0] = 0.f; acc[mt][nt][1] = 0.f;
      acc[mt][nt][2] = 0.f; acc[mt][nt][3] = 0.f;
    }

  const int nchunk = K >> 5;
  for (int c = 0; c < nchunk; ++c) {
    glds16(pAh0, lA0); glds16(pAh1, lA1);
    glds16(pBh0, lB0); glds16(pBh1, lB1);
    if constexpr (SPLIT) {
      glds16(pAl0, AlS + (w * 32) * 32);
      glds16(pAl1, AlS + (w * 32 + 16) * 32);
      glds16(pBl0, BlS + (w * 32) * 32);
      glds16(pBl1, BlS + (w * 32 + 16) * 32);
    }
    pAh0 += 32; pAh1 += 32; pBh0 += 32; pBh1 += 32;
    if constexpr (SPLIT) { pAl0 += 32; pAl1 += 32; pBl0 += 32; pBl1 += 32; }
    __syncthreads();

    if constexpr (SPLIT) {
      short8 afh[2], afl[2];
#pragma unroll
      for (int mt = 0; mt < 2; ++mt) {
        afh[mt] = *(const short8*)&AhS[(w * 32 + mt * 16 + col16) * 32 + quad * 8];
        afl[mt] = *(const short8*)&AlS[(w * 32 + mt * 16 + col16) * 32 + quad * 8];
      }
#pragma unroll
      for (int nt = 0; nt < 8; ++nt) {
        short8 bh = *(const short8*)&BhS[(nt * 16 + col16) * 32 + quad * 8];
        short8 bl = *(const short8*)&BlS[(nt * 16 + col16) * 32 + quad * 8];
#pragma unroll
        for (int mt = 0; mt < 2; ++mt) {
          acc[mt][nt] = __builtin_amdgcn_mfma_f32_16x16x32_bf16(afh[mt], bh, acc[mt][nt], 0, 0, 0);
          acc[mt][nt] = __builtin_amdgcn_mfma_f32_16x16x32_bf16(afl[mt], bh, acc[mt][nt], 0, 0, 0);
          acc[mt][nt] = __builtin_amdgcn_mfma_f32_16x16x32_bf16(afh[mt], bl, acc[mt][nt], 0, 0, 0);
        }
      }
    } else {
      half8 af[2];
#pragma unroll
      for (int mt = 0; mt < 2; ++mt)
        af[mt] = *(const half8*)&AhS[(w * 32 + mt * 16 + col16) * 32 + quad * 8];
#pragma unroll
      for (int nt = 0; nt < 8; ++nt) {
        half8 bh = *(const half8*)&BhS[(nt * 16 + col16) * 32 + quad * 8];
#pragma unroll
        for (int mt = 0; mt < 2; ++mt)
          acc[mt][nt] = __builtin_amdgcn_mfma_f32_16x16x32_f16(af[mt], bh, acc[mt][nt], 0, 0, 0);
      }
    }
    __syncthreads();
  }

#pragma unroll
  for (int mt = 0; mt < 2; ++mt)
#pragma unroll
    for (int nt = 0; nt < 8; ++nt)
#pragma unroll
      for (int r = 0; r < 4; ++r) {
        int row = row0 + w * 32 + mt * 16 + quad * 4 + r;
        int col = col0 + nt * 16 + col16;
        float v = acc[mt][nt][r];
        if constexpr (SPLIT) {
          Cf[(size_t)row * N + col] = (_Float16)(v * esc);
        } else {
          C[(size_t)row * N + col] = v;
        }
      }
}

// ---------------------------------------------------------------------------
// build VT (fp16 bits) [2][128][2048] from fused proj cols 2176..2303
// ---------------------------------------------------------------------------
__global__ __launch_bounds__(256) void build_vt(
    const short* __restrict__ QKf, short* __restrict__ VT) {
  __shared__ short T[64][136];
  const int tid = threadIdx.x;
  const int gs = blockIdx.x * 64;
  const int b = gs >> 11;
  const int s = gs & 2047;
  {
    int r = tid >> 2, c0 = (tid & 3) * 32;
    const short* src = QKf + (size_t)(gs + r) * NFUSE + 2176 + c0;
#pragma unroll
    for (int j = 0; j < 4; ++j)
      *(short8*)&T[r][c0 + 8 * j] = *(const short8*)(src + 8 * j);
  }
  __syncthreads();
  {
    int d = tid >> 1, c = (tid & 1) * 32;
    short* dst = VT + (size_t)(b * HDIM + d) * S_LEN + s + c;
#pragma unroll
    for (int jo = 0; jo < 4; ++jo) {
      short8 o;
#pragma unroll
      for (int i = 0; i < 8; ++i) o[i] = T[c + jo * 8 + i][d];
      *(short8*)(dst + jo * 8) = o;
    }
  }
}

// ---------------------------------------------------------------------------
// fp16 MFMA flash attention. BM=128 (2 Q-tiles/wave), BN=64.
// glds + XOR-swizzled unpadded LDS for Q/K/V staging (conflict-free reads).
// Logits in log2 domain (Q pre-scaled by log2e; mask scaled at load).
// grid (S/128, B*H), 256 threads = 4 waves, 3 blocks/CU.
// ---------------------------------------------------------------------------
#define LDP 72

__global__ __launch_bounds__(256, 3) void flash_mfma(
    const _Float16* __restrict__ QKf, const _Float16* __restrict__ VT,
    const float* __restrict__ mask, _Float16* __restrict__ AO) {
  __shared__ short KfS[64 * 128];    // rows 0..63, 16 chunks of 16B, XOR-swizzled
  __shared__ short VtS[128 * 64];    // rows 0..127 (dims), 8 chunks, XOR-swizzled
  __shared__ short PsS[2][4][16 * LDP];

  const int tid   = threadIdx.x;
  const int w     = tid >> 6;
  const int lane  = tid & 63;
  const int quad  = lane >> 4;
  const int col16 = lane & 15;
  const int xm8   = (col16 & 7) << 3;   // short-index XOR mask for swizzle
  const int bh = blockIdx.y, b = bh >> 4, h = bh & 15;
  const int t0 = blockIdx.x * 128;

  // ---- stage Q tiles via glds (swizzled), extract A-fragments
  half8 qf[2][4];
#pragma unroll
  for (int t = 0; t < 2; ++t) {
#pragma unroll
    for (int i = 0; i < 4; ++i) {
      int r = w * 16 + i * 4 + (lane >> 4);
      const _Float16* g = QKf + (size_t)(b * S_LEN + t0 + t * 64 + r) * NFUSE
                        + h * HDIM + (((lane & 15) ^ (r & 7)) << 3);
      glds16(g, KfS + (w * 16 + i * 4) * 128);
    }
    __syncthreads();
#pragma unroll
    for (int c = 0; c < 4; ++c)
      qf[t][c] = *(const half8*)&KfS[(16 * w + col16) * 128 + (((4 * c + quad) * 8) ^ xm8)];
    __syncthreads();
  }

  f32x4 oacc[2][8];
#pragma unroll
  for (int t = 0; t < 2; ++t)
#pragma unroll
    for (int d = 0; d < 8; ++d) {
      oacc[t][d][0] = 0.f; oacc[t][d][1] = 0.f;
      oacc[t][d][2] = 0.f; oacc[t][d][3] = 0.f;
    }
  float mrow[2][4], lrow[2][4];
#pragma unroll
  for (int t = 0; t < 2; ++t)
#pragma unroll
    for (int r = 0; r < 4; ++r) { mrow[t][r] = -3.0e38f; lrow[t][r] = 0.f; }

  const float* mbase = mask + (size_t)b * S_LEN * S_LEN
                     + (size_t)(t0 + 16 * w + quad * 4) * S_LEN + col16;

  for (int s0 = 0; s0 < S_LEN; s0 += 64) {
    __syncthreads();   // prior iteration's LDS reads done
    // ---- stage K [64][128] and V^T [128][64] via glds (swizzled)
#pragma unroll
    for (int i = 0; i < 4; ++i) {
      int rk = w * 16 + i * 4 + (lane >> 4);
      const _Float16* gk = QKf + (size_t)(b * S_LEN + s0 + rk) * NFUSE + 2048
                         + (((lane & 15) ^ (rk & 7)) << 3);
      glds16(gk, KfS + (w * 16 + i * 4) * 128);
      int rv = w * 32 + i * 8 + (lane >> 3);
      const _Float16* gv = VT + (size_t)(b * HDIM + rv) * S_LEN + s0
                         + (((lane & 7) ^ (rv & 7)) << 3);
      glds16(gv, VtS + (w * 32 + i * 8) * 64);
    }
    // ---- mask tile 0 loads (drained by the barrier below)
    float m0[4][4];
    {
      const float* mp = mbase + s0;
#pragma unroll
      for (int r = 0; r < 4; ++r)
#pragma unroll
        for (int nt = 0; nt < 4; ++nt)
          m0[r][nt] = mp[(size_t)r * S_LEN + nt * 16] * LOG2E;
    }
    __syncthreads();   // glds data visible
    // ---- mask tile 1 loads (overlap QK MFMAs)
    float m1[4][4];
    {
      const float* mp = mbase + (size_t)64 * S_LEN + s0;
#pragma unroll
      for (int r = 0; r < 4; ++r)
#pragma unroll
        for (int nt = 0; nt < 4; ++nt)
          m1[r][nt] = mp[(size_t)r * S_LEN + nt * 16] * LOG2E;
    }

    // ---- QK (single-term fp16), K-fragments shared across both Q-tiles
    f32x4 sacc[2][4];
#pragma unroll
    for (int t = 0; t < 2; ++t)
#pragma unroll
      for (int nt = 0; nt < 4; ++nt) {
        sacc[t][nt][0] = 0.f; sacc[t][nt][1] = 0.f;
        sacc[t][nt][2] = 0.f; sacc[t][nt][3] = 0.f;
      }
#pragma unroll
    for (int c = 0; c < 4; ++c)
#pragma unroll
      for (int nt = 0; nt < 4; ++nt) {
        half8 k8 = *(const half8*)&KfS[(nt * 16 + col16) * 128 + (((4 * c + quad) * 8) ^ xm8)];
        sacc[0][nt] = __builtin_amdgcn_mfma_f32_16x16x32_f16(qf[0][c], k8, sacc[0][nt], 0, 0, 0);
        sacc[1][nt] = __builtin_amdgcn_mfma_f32_16x16x32_f16(qf[1][c], k8, sacc[1][nt], 0, 0, 0);
      }

    // ---- online softmax (base-2) per tile; P stored as fp16
#pragma unroll
    for (int t = 0; t < 2; ++t) {
      float alr[4];
#pragma unroll
      for (int r = 0; r < 4; ++r) {
        float v0 = sacc[t][0][r] + (t ? m1[r][0] : m0[r][0]);
        float v1 = sacc[t][1][r] + (t ? m1[r][1] : m0[r][1]);
        float v2 = sacc[t][2][r] + (t ? m1[r][2] : m0[r][2]);
        float v3 = sacc[t][3][r] + (t ? m1[r][3] : m0[r][3]);
        float mx = fmaxf(fmaxf(v0, v1), fmaxf(v2, v3));
        mx = fmaxf(mx, __shfl_xor(mx, 1));
        mx = fmaxf(mx, __shfl_xor(mx, 2));
        mx = fmaxf(mx, __shfl_xor(mx, 4));
        mx = fmaxf(mx, __shfl_xor(mx, 8));
        float nm = fmaxf(mrow[t][r], mx);
        union { _Float16 h; short s; } h0, h1, h2, h3;
        h0.h = (_Float16)fexp2(v0 - nm);
        h1.h = (_Float16)fexp2(v1 - nm);
        h2.h = (_Float16)fexp2(v2 - nm);
        h3.h = (_Float16)fexp2(v3 - nm);
        // sum the ROUNDED p so numerator/denominator rounding cancels
        float ps = ((float)h0.h + (float)h1.h) + ((float)h2.h + (float)h3.h);
        ps += __shfl_xor(ps, 1);
        ps += __shfl_xor(ps, 2);
        ps += __shfl_xor(ps, 4);
        ps += __shfl_xor(ps, 8);
        float al = fexp2(mrow[t][r] - nm);
        lrow[t][r] = lrow[t][r] * al + ps;
        mrow[t][r] = nm;
        alr[r] = al;
        int pbase = (quad * 4 + r) * LDP + col16;
        PsS[t][w][pbase +  0] = h0.s;
        PsS[t][w][pbase + 16] = h1.s;
        PsS[t][w][pbase + 32] = h2.s;
        PsS[t][w][pbase + 48] = h3.s;
      }
#pragma unroll
      for (int d = 0; d < 8; ++d)
#pragma unroll
        for (int r = 0; r < 4; ++r) oacc[t][d][r] *= alr[r];
    }

    __asm__ volatile("s_waitcnt lgkmcnt(0)" ::: "memory");  // P visible in-wave

    // ---- PV: V-fragments read once, used by both tiles
    half8 pa[2][2];
#pragma unroll
    for (int t = 0; t < 2; ++t) {
      pa[t][0] = *(const half8*)&PsS[t][w][col16 * LDP + quad * 8];
      pa[t][1] = *(const half8*)&PsS[t][w][col16 * LDP + 32 + quad * 8];
    }
#pragma unroll
    for (int d = 0; d < 8; ++d) {
      const int rv = (d * 16 + col16) * 64;
      half8 vb0 = *(const half8*)&VtS[rv + ((quad * 8) ^ xm8)];
      half8 vb1 = *(const half8*)&VtS[rv + (((quad + 4) * 8) ^ xm8)];
#pragma unroll
      for (int t = 0; t < 2; ++t) {
        oacc[t][d] = __builtin_amdgcn_mfma_f32_16x16x32_f16(pa[t][0], vb0, oacc[t][d], 0, 0, 0);
        oacc[t][d] = __builtin_amdgcn_mfma_f32_16x16x32_f16(pa[t][1], vb1, oacc[t][d], 0, 0, 0);
      }
    }
  }

  // ---- epilogue: normalize, store fp16 AO [4096][2048]
#pragma unroll
  for (int t = 0; t < 2; ++t)
#pragma unroll
    for (int r = 0; r < 4; ++r) {
      float inv = 1.0f / lrow[t][r];
      _Float16* dst = AO + (size_t)(b * S_LEN + t0 + t * 64 + 16 * w + quad * 4 + r) * EMB
                    + h * HDIM + col16;
#pragma unroll
      for (int d = 0; d < 8; ++d) dst[d * 16] = (_Float16)(oacc[t][d][r] * inv);
    }
}

// ---------------------------------------------------------------------------
extern "C" void kernel_launch(void* const* d_in, const int* in_sizes, int n_in,
                              void* d_out, int out_size, void* d_ws, size_t ws_size,
                              hipStream_t stream) {
  const float* x    = (const float*)d_in[0];
  const float* mask = (const float*)d_in[1];
  const float* W1   = (const float*)d_in[2];
  const float* W2   = (const float*)d_in[3];
  const float* W3   = (const float*)d_in[4];
  float* out = (float*)d_out;

  char* ws = (char*)d_ws;
  size_t off = 0;
  short*     xh  = (short*)(ws + off);     off += (size_t)4096 * 2048 * 2;   // 16 MiB
  short*     xl  = (short*)(ws + off);     off += (size_t)4096 * 2048 * 2;   // 16 MiB
  short*     Wth = (short*)(ws + off);     off += (size_t)NFUSE * 2048 * 2;  //  9 MiB
  short*     Wtl = (short*)(ws + off);     off += (size_t)NFUSE * 2048 * 2;  //  9 MiB
  _Float16*  QKf = (_Float16*)(ws + off);  off += (size_t)4096 * NFUSE * 2;  // 18 MiB
  _Float16*  VT  = (_Float16*)(ws + off);  off += (size_t)2 * 128 * 2048 * 2;//  1 MiB
  _Float16*  AOh = (_Float16*)(ws + off);  off += (size_t)4096 * 2048 * 2;   // 16 MiB
  float*     Wkv = (float*)(ws + off);     off += (size_t)2048 * 256 * 4;    //  2 MiB
  short*     W3t = xh;  // alias: xh dead after fused GEMM; W3 transpose runs after

  // 1) prep
  reduce_w1_kernel<<<2048, 256, 0, stream>>>(W1, Wkv);
  split_f32_kernel<<<8192, 256, 0, stream>>>(x, xh, xl);
  transpose_split_kernel<0><<<dim3(32, 32), 256, 0, stream>>>(W2, Wth, Wtl, 2048, 2048);
  transpose_split_kernel<0><<<dim3(4, 32), 256, 0, stream>>>(
      Wkv, Wth + (size_t)2048 * 2048, Wtl + (size_t)2048 * 2048, 2048, 256);

  // 2) fused projection GEMM (split-bf16 internal, fp16 out; Q cols ×log2e)
  gemm_mfma<true><<<dim3(NFUSE / 128, 32), 256, 32768, stream>>>(
      xh, xl, Wth, Wtl, nullptr, QKf, 4096, NFUSE, 2048, 2048);

  // 3) V^T extraction
  build_vt<<<64, 256, 0, stream>>>((const short*)QKf, (short*)VT);

  // 4) attention
  flash_mfma<<<dim3(S_LEN / 128, 2 * NHEAD), 256, 0, stream>>>(
      QKf, VT, mask, AOh);

  // 5) output projection (fp16 single-term)
  transpose_split_kernel<1><<<dim3(32, 32), 256, 0, stream>>>(W3, W3t, nullptr, 2048, 2048);
  gemm_mfma<false><<<dim3(16, 32), 256, 16384, stream>>>(
      (const short*)AOh, nullptr, W3t, nullptr, out, nullptr, 4096, 2048, 2048, 0);
}